// Round 1
// baseline (157.652 us; speedup 1.0000x reference)
//
#include <hip/hip_runtime.h>
#include <math.h>

// Problem constants (from reference): B=1048576, DX=32, DS=16, H=128, K=64, NSN=4
#define DXc 32
#define DSc 16
#define Hc  128
#define Kc  64
#define NSNc 4

__global__ __launch_bounds__(256, 4) void snclust_fused(
    const float* __restrict__ x,
    const float* __restrict__ s,
    const float* __restrict__ hidden,
    const float* __restrict__ naive_pred,
    const float* __restrict__ centers,
    const float* __restrict__ W_tune,
    const float* __restrict__ b_tune,
    const float* __restrict__ W_sn,
    const float* __restrict__ b_sn,
    const float* __restrict__ rsw,
    float* __restrict__ out,
    int n)
{
    // Combined SN weights: Wc[c][j] = sum_n rsw[c,n] * W_sn[n,c,j]
    //                      bc[c]    = sum_n rsw[c,n] * b_sn[n,c]
    // Pad rows to 17 floats so divergent-cluster reads spread across banks.
    __shared__ float sWc[Kc][DSc + 1];
    __shared__ float sbc[Kc];
    __shared__ float sc2[Kc];

    const int tid = threadIdx.x;

    for (int e = tid; e < Kc * DSc; e += 256) {
        const int c = e >> 4;
        const int j = e & 15;
        float acc = 0.f;
#pragma unroll
        for (int nn = 0; nn < NSNc; ++nn)
            acc = fmaf(rsw[c * NSNc + nn], W_sn[(nn * Kc + c) * DSc + j], acc);
        sWc[c][j] = acc;
    }
    if (tid < Kc) {
        const int c = tid;
        float accb = 0.f;
#pragma unroll
        for (int nn = 0; nn < NSNc; ++nn)
            accb = fmaf(rsw[c * NSNc + nn], b_sn[nn * Kc + c], accb);
        sbc[c] = accb;
        float c2 = 0.f;
#pragma unroll
        for (int d = 0; d < DXc; ++d) {
            const float cv = centers[c * DXc + d];
            c2 = fmaf(cv, cv, c2);
        }
        sc2[c] = c2;
    }
    __syncthreads();

    const int b = blockIdx.x * 256 + tid;
    if (b >= n) return;

    // ---- x row into registers (8x float4) ----
    float xr[DXc];
    {
        const float4* x4 = reinterpret_cast<const float4*>(x + (size_t)b * DXc);
#pragma unroll
        for (int i = 0; i < DXc / 4; ++i) {
            const float4 v = x4[i];
            xr[i * 4 + 0] = v.x;
            xr[i * 4 + 1] = v.y;
            xr[i * 4 + 2] = v.z;
            xr[i * 4 + 3] = v.w;
        }
    }

    // ---- x_tune = sigmoid(hidden . W_tune + b_tune) ----
    // W_tune reads are wave-uniform -> SGPR (s_load); hidden via float4.
    float hacc = 0.f;
    {
        const float4* h4 = reinterpret_cast<const float4*>(hidden + (size_t)b * Hc);
#pragma unroll 8
        for (int i = 0; i < Hc / 4; ++i) {
            const float4 v = h4[i];
            hacc = fmaf(v.x, W_tune[i * 4 + 0], hacc);
            hacc = fmaf(v.y, W_tune[i * 4 + 1], hacc);
            hacc = fmaf(v.z, W_tune[i * 4 + 2], hacc);
            hacc = fmaf(v.w, W_tune[i * 4 + 3], hacc);
        }
    }
    const float z = hacc + b_tune[0];
    const float x_tune = 1.0f / (1.0f + __expf(-z));

    // ---- argmin_k ( c2[k] - 2 * x . centers[k] ) ----
    // centers reads are wave-uniform -> scalar loads + SGPR-source FMAs.
    int bestk = 0;
    float bestd = INFINITY;
#pragma unroll 2
    for (int k = 0; k < Kc; ++k) {
        float dot = 0.f;
#pragma unroll
        for (int d = 0; d < DXc; ++d)
            dot = fmaf(xr[d], centers[k * DXc + d], dot);
        const float dist = fmaf(-2.0f, dot, sc2[k]);
        if (dist < bestd) { bestd = dist; bestk = k; }
    }

    // ---- combined SN dot ----
    float snacc = sbc[bestk];
    {
        const float4* s4 = reinterpret_cast<const float4*>(s + (size_t)b * DSc);
#pragma unroll
        for (int i = 0; i < DSc / 4; ++i) {
            const float4 v = s4[i];
            snacc = fmaf(v.x, sWc[bestk][i * 4 + 0], snacc);
            snacc = fmaf(v.y, sWc[bestk][i * 4 + 1], snacc);
            snacc = fmaf(v.z, sWc[bestk][i * 4 + 2], snacc);
            snacc = fmaf(v.w, sWc[bestk][i * 4 + 3], snacc);
        }
    }

    const float np_ = naive_pred[b];
    out[b] = snacc + x_tune * (np_ - snacc);
}

extern "C" void kernel_launch(void* const* d_in, const int* in_sizes, int n_in,
                              void* d_out, int out_size, void* d_ws, size_t ws_size,
                              hipStream_t stream) {
    const float* x          = (const float*)d_in[0];
    const float* s          = (const float*)d_in[1];
    const float* hidden     = (const float*)d_in[2];
    const float* naive_pred = (const float*)d_in[3];
    const float* centers    = (const float*)d_in[4];
    const float* W_tune     = (const float*)d_in[5];
    const float* b_tune     = (const float*)d_in[6];
    const float* W_sn       = (const float*)d_in[7];
    const float* b_sn       = (const float*)d_in[8];
    const float* rsw        = (const float*)d_in[9];
    float* out = (float*)d_out;

    const int n = in_sizes[3];  // B (naive_pred element count)
    const int blocks = (n + 255) / 256;
    snclust_fused<<<blocks, 256, 0, stream>>>(x, s, hidden, naive_pred, centers,
                                              W_tune, b_tune, W_sn, b_sn, rsw,
                                              out, n);
}